// Round 7
// baseline (298.629 us; speedup 1.0000x reference)
//
#include <hip/hip_runtime.h>
#include <hip/hip_bf16.h>

typedef unsigned int u32;
typedef unsigned short u16;
using bf16x8 = __attribute__((ext_vector_type(8))) short;
using f32x4  = __attribute__((ext_vector_type(4))) float;

#define S_LEN 2048
#define DK 64
#define NH 16
#define DMODEL 1024
#define NROWS 4096   // B * S

// ---------- helpers ----------
__device__ __forceinline__ u16 f2bf(float f){
  u32 u = __builtin_bit_cast(u32, f);
  u += 0x7fffu + ((u >> 16) & 1u);   // round-to-nearest-even
  return (u16)(u >> 16);
}

__device__ __forceinline__ float bf2f(u16 h){
  return __builtin_bit_cast(float, (u32)h << 16);
}

__device__ __forceinline__ void gload_lds16(const u16* g, u16* l){
  // async global->LDS, 16B per lane; LDS dest = wave-uniform base + lane*16
  __builtin_amdgcn_global_load_lds(
      (__attribute__((address_space(1))) u32*)(void*)const_cast<u16*>(g),
      (__attribute__((address_space(3))) u32*)(void*)l, 16, 0, 0);
}

// counted-vmcnt barrier: 2 staging loads (oldest) done, 4 emit stores in flight
#define TILE_BARRIER_VM4() do { \
  asm volatile("s_waitcnt vmcnt(4) lgkmcnt(0)" ::: "memory"); \
  __builtin_amdgcn_s_barrier(); \
  __builtin_amdgcn_sched_barrier(0); \
} while (0)

#define TILE_BARRIER_VM0() do { \
  asm volatile("s_waitcnt vmcnt(0) lgkmcnt(0)" ::: "memory"); \
  __builtin_amdgcn_s_barrier(); \
  __builtin_amdgcn_sched_barrier(0); \
} while (0)

// ---------- f32 -> bf16 conversion, all 7 tensors in one launch ----------
__global__ void cvt_all(const float* __restrict__ q, const float* __restrict__ k,
                        const float* __restrict__ v, const float* __restrict__ wq,
                        const float* __restrict__ wk, const float* __restrict__ wv,
                        const float* __restrict__ wo, u16* __restrict__ ws)
{
  const int y = blockIdx.y;
  const int n4 = (y < 3) ? (NROWS*DMODEL/4) : (DMODEL*DMODEL/4);
  const int i = blockIdx.x * blockDim.x + threadIdx.x;
  if (i >= n4) return;
  const float* src = (y==0)?q:(y==1)?k:(y==2)?v:(y==3)?wq:(y==4)?wk:(y==5)?wv:wo;
  u16* dst = ws + ((y < 3) ? (size_t)y*(NROWS*DMODEL)
                           : (size_t)3*(NROWS*DMODEL) + (size_t)(y-3)*(DMODEL*DMODEL));
  float4 val = reinterpret_cast<const float4*>(src)[i];
  ushort4 o;
  o.x = f2bf(val.x); o.y = f2bf(val.y); o.z = f2bf(val.z); o.w = f2bf(val.w);
  reinterpret_cast<ushort4*>(dst)[i] = o;
}

// ---------- GEMM core (m97 structure): C[m,n] = sum_k A[m,k]*Bt[n,k], K=1024 ----------
template<bool OUTGEMM>
__global__ __launch_bounds__(256)
void gemm_mha(const u16* __restrict__ Abase, const u16* __restrict__ Bbase,
              u16* __restrict__ Qh, u16* __restrict__ Kh, u16* __restrict__ Vt,
              float* __restrict__ Out, const float* __restrict__ bias)
{
  __shared__ u16 smem[32768];          // 64 KiB: As [2][8192] | Bs [2][8192]
  u16* As = smem;
  u16* Bs = smem + 16384;

  const int tid  = threadIdx.x;
  const int lane = tid & 63;
  const int wid  = tid >> 6;            // 4 waves
  const int lo = lane & 15, hi = lane >> 4;
  const int z = OUTGEMM ? 0 : blockIdx.z;
  const int m0 = blockIdx.x * 128;
  const int n0 = blockIdx.y * 128;
  const u16* ga = Abase + (size_t)z * (NROWS*DMODEL)  + (size_t)m0 * DMODEL;
  const u16* gb = Bbase + (size_t)z * (DMODEL*DMODEL) + (size_t)n0 * DMODEL;

  const int wm = (wid >> 1) * 64;
  const int wn = (wid & 1) * 64;

  f32x4 acc[4][4] = {};

  auto stage = [&](int buf, int kt){
    const u16* a = ga + kt * 64;
    const u16* b = gb + kt * 64;
    #pragma unroll
    for (int i = 0; i < 4; ++i){
      const int chunk = i*256 + tid;    // 1024 16B-chunks (128 rows x 8)
      const int row = chunk >> 3, c8 = chunk & 7;
      gload_lds16(a + (size_t)row*DMODEL + c8*8, &As[buf*8192 + (i*256 + wid*64)*8]);
      gload_lds16(b + (size_t)row*DMODEL + c8*8, &Bs[buf*8192 + (i*256 + wid*64)*8]);
    }
  };

  stage(0, 0);
  __syncthreads();

  for (int t = 0; t < DMODEL/64; ++t){
    const int buf = t & 1;
    if (t + 1 < DMODEL/64) stage(buf ^ 1, t + 1);
    const u16* as = &As[buf*8192];
    const u16* bs = &Bs[buf*8192];
    #pragma unroll
    for (int ks = 0; ks < 2; ++ks){
      bf16x8 af[4], bfr[4];
      #pragma unroll
      for (int i = 0; i < 4; ++i){
        af[i]  = *reinterpret_cast<const bf16x8*>(&as[(wm + i*16 + lo)*64 + ks*32 + hi*8]);
        bfr[i] = *reinterpret_cast<const bf16x8*>(&bs[(wn + i*16 + lo)*64 + ks*32 + hi*8]);
      }
      #pragma unroll
      for (int mi = 0; mi < 4; ++mi)
        #pragma unroll
        for (int ni = 0; ni < 4; ++ni)
          acc[mi][ni] = __builtin_amdgcn_mfma_f32_16x16x32_bf16(af[mi], bfr[ni], acc[mi][ni], 0, 0, 0);
    }
    __syncthreads();
  }

  // C/D layout: col = lane&15 (lo), row = hi*4 + r
  if constexpr (OUTGEMM){
    #pragma unroll
    for (int mi = 0; mi < 4; ++mi)
    #pragma unroll
    for (int ni = 0; ni < 4; ++ni)
    #pragma unroll
    for (int r = 0; r < 4; ++r){
      const int m = m0 + wm + mi*16 + hi*4 + r;
      const int n = n0 + wn + ni*16 + lo;
      Out[(size_t)m * DMODEL + n] = acc[mi][ni][r] + bias[n];
    }
  } else {
    // LDS transpose epilogue; row pitch 136 keeps 16B alignment, banks spread
    const float scale = (z == 0) ? 0.18033688011112043f : 1.0f;  // log2(e)/8
    if (z == 2){
      #pragma unroll
      for (int mi = 0; mi < 4; ++mi)
      #pragma unroll
      for (int ni = 0; ni < 4; ++ni)
      #pragma unroll
      for (int r = 0; r < 4; ++r)
        smem[(size_t)(wn + ni*16 + lo)*136 + wm + mi*16 + hi*4 + r] = f2bf(acc[mi][ni][r]);
    } else {
      #pragma unroll
      for (int mi = 0; mi < 4; ++mi)
      #pragma unroll
      for (int ni = 0; ni < 4; ++ni)
      #pragma unroll
      for (int r = 0; r < 4; ++r)
        smem[(size_t)(wm + mi*16 + hi*4 + r)*136 + wn + ni*16 + lo] = f2bf(acc[mi][ni][r] * scale);
    }
    __syncthreads();
    const int b = m0 >> 11, s0 = m0 & 2047;
    #pragma unroll
    for (int it = 0; it < 8; ++it){
      const int c = it*256 + tid;       // 2048 chunks of 8 elements
      const int rr = c >> 4, cc = c & 15;
      bf16x8 v = *reinterpret_cast<const bf16x8*>(&smem[(size_t)rr*136 + cc*8]);
      if (z == 2){
        const int gn = n0 + rr, h = gn >> 6, d = gn & 63;
        *reinterpret_cast<bf16x8*>(&Vt[(((size_t)(b*NH + h))*DK + d)*S_LEN + s0 + cc*8]) = v;
      } else {
        const int gn = n0 + cc*8, h = gn >> 6, d0 = gn & 63;
        u16* dst = z ? Kh : Qh;
        *reinterpret_cast<bf16x8*>(&dst[(((size_t)(b*NH + h))*S_LEN + s0 + rr)*DK + d0]) = v;
      }
    }
  }
}

// ---------- fused attention: P supertile + streaming 512B-run emission ----------
// 512 blocks (XCD-swizzled), 512 threads = 8 waves x 16 q-rows (128 q/block).
// Pass 2 accumulates P (bf16) into a double-buffered 128x128 LDS supertile
// (per-wave-exclusive rows -> no P barriers); previous supertile is emitted as
// contiguous 512B f32 row-runs, issued ahead of compute, kept in flight via
// counted vmcnt. K/V double-buffered via global_load_lds (XOR-chunk swizzle).
__global__ __launch_bounds__(512)
void attn_fused(const u16* __restrict__ Qh, const u16* __restrict__ Kh,
                const u16* __restrict__ Vt, float* __restrict__ attn,
                u16* __restrict__ ctx)
{
  constexpr int S = S_LEN;
  constexpr int PP = 132;            // P supertile pitch (u16)
  __shared__ u16 Ks[2][64*64];       // 16 KiB, swizzled
  __shared__ u16 Vs[2][64*64];       // 16 KiB, swizzled
  __shared__ u16 Ps[2*128*PP];       // 66 KiB, bf16 P supertile double-buffer

  const int tid = threadIdx.x, lane = tid & 63, w = tid >> 6;   // 8 waves
  const int lo = lane & 15, hi = lane >> 4;

  // bijective XCD mapping: 16 q-tiles of one (b,h) share an XCD
  const int idx = blockIdx.x;
  const int slot = idx >> 3;
  const int qt = slot & 15;
  const int bh = (idx & 7) + 8 * (slot >> 4);

  const int q0 = qt*128 + w*16;      // this wave's 16 q rows
  const u16* Qb = Qh + (size_t)bh * S * DK;
  const u16* Kb = Kh + (size_t)bh * S * DK;
  const u16* Vb = Vt + (size_t)bh * DK * S;
  float* attn_b = attn + (size_t)bh * S * S;

  // Q fragments in registers for the whole kernel
  bf16x8 aq[2];
  #pragma unroll
  for (int ks = 0; ks < 2; ++ks)
    aq[ks] = *reinterpret_cast<const bf16x8*>(
        &Qb[(size_t)(q0 + lo) * DK + ks*32 + hi*8]);

  // swizzled staging: LDS[r][c] (16B chunks) <- G[r][c ^ (r&7)]; 1 chunk/lane
  const int sr = tid >> 3, sc = tid & 7;
  auto stageK = [&](int buf, int t){
    gload_lds16(Kb + (size_t)t*64*DK + (size_t)sr*DK + ((sc ^ (sr&7))*8),
                &Ks[buf][w*512]);
  };
  auto stageV = [&](int buf, int t){
    gload_lds16(Vb + (size_t)sr*S + t*64 + ((sc ^ (sr&7))*8),
                &Vs[buf][w*512]);
  };

  auto qk = [&](int buf, f32x4 (&s)[4]){
    #pragma unroll
    for (int ks = 0; ks < 2; ++ks){
      bf16x8 bk[4];
      #pragma unroll
      for (int kf = 0; kf < 4; ++kf){
        const int row = kf*16 + lo;
        bk[kf] = *reinterpret_cast<const bf16x8*>(
            &Ks[buf][row*64 + (((ks*4 + hi) ^ (row&7))*8)]);
      }
      #pragma unroll
      for (int kf = 0; kf < 4; ++kf)
        s[kf] = __builtin_amdgcn_mfma_f32_16x16x32_bf16(aq[ks], bk[kf], s[kf], 0, 0, 0);
    }
  };

  // ---- pass 1: lane-local sum of exp2(s') ----
  stageK(0, 0);
  __syncthreads();
  float l_part[4] = {};
  for (int t = 0; t < S/64; ++t){
    const int buf = t & 1;
    if (t + 1 < S/64) stageK(buf ^ 1, t + 1);
    f32x4 s[4] = {};
    qk(buf, s);
    #pragma unroll
    for (int r = 0; r < 4; ++r)
      l_part[r] += exp2f(s[0][r]) + exp2f(s[1][r]) + exp2f(s[2][r]) + exp2f(s[3][r]);
    __syncthreads();
  }

  float inv_l[4];
  #pragma unroll
  for (int r = 0; r < 4; ++r){
    float v = l_part[r];
    v += __shfl_xor(v, 1, 64);
    v += __shfl_xor(v, 2, 64);
    v += __shfl_xor(v, 4, 64);
    v += __shfl_xor(v, 8, 64);
    inv_l[r] = 1.0f / v;
  }

  // ---- pass 2: P supertile (128 kv = 2 subtiles), deferred streaming emit ----
  const int el = lane & 31, eh = lane >> 5;   // emit lane split: 2 rows/instr
  auto emit4 = [&](int slab, int st_idx, int jbase){
    #pragma unroll
    for (int j = 0; j < 4; ++j){
      const int r0 = jbase + j*2 + eh;
      ushort4 p4 = *reinterpret_cast<const ushort4*>(
          &Ps[(size_t)(slab*128 + w*16 + r0)*PP + el*4]);
      f32x4 fv;
      fv[0] = bf2f(p4.x); fv[1] = bf2f(p4.y); fv[2] = bf2f(p4.z); fv[3] = bf2f(p4.w);
      *reinterpret_cast<f32x4*>(
          &attn_b[(size_t)(q0 + r0)*S + st_idx*128 + el*4]) = fv;
    }
  };

  stageK(0, 0); stageV(0, 0);
  TILE_BARRIER_VM0();
  f32x4 o[4] = {};
  for (int t = 0; t < S/64; ++t){
    const int buf = t & 1, st = t >> 1, sub = t & 1, pb = st & 1;
    // 1. issue next-tile staging first (loads precede emit stores in vmcnt FIFO)
    if (t + 1 < S/64){ stageK(buf ^ 1, t + 1); stageV(buf ^ 1, t + 1); }
    // 2. emit previous supertile: 4 instr x (2 rows x 512B contiguous)
    if (st >= 1) emit4(pb ^ 1, st - 1, sub*8);
    // 3. QK^T
    f32x4 s[4] = {};
    qk(buf, s);
    // 4. normalized p -> bf16 into own supertile rows (per-wave exclusive)
    #pragma unroll
    for (int kf = 0; kf < 4; ++kf)
      #pragma unroll
      for (int r = 0; r < 4; ++r){
        const float p = exp2f(s[kf][r]) * inv_l[r];
        Ps[(size_t)(pb*128 + w*16 + hi*4 + r)*PP + sub*64 + kf*16 + lo] = f2bf(p);
      }
    // 5. PV from supertile (same-wave DS in-order; no barrier)
    #pragma unroll
    for (int ks = 0; ks < 2; ++ks){
      bf16x8 ap = *reinterpret_cast<const bf16x8*>(
          &Ps[(size_t)(pb*128 + w*16 + lo)*PP + sub*64 + ks*32 + hi*8]);
      bf16x8 bv[4];
      #pragma unroll
      for (int df = 0; df < 4; ++df){
        const int vrow = df*16 + lo;
        bv[df] = *reinterpret_cast<const bf16x8*>(
            &Vs[buf][vrow*64 + (((ks*4 + hi) ^ (vrow&7))*8)]);
      }
      #pragma unroll
      for (int df = 0; df < 4; ++df)
        o[df] = __builtin_amdgcn_mfma_f32_16x16x32_bf16(ap, bv[df], o[df], 0, 0, 0);
    }
    // 6. tile barrier: staging loads retired; emit stores stay in flight
    if (t + 1 < S/64){
      if (st == 0) { TILE_BARRIER_VM0(); } else { TILE_BARRIER_VM4(); }
    }
  }
  // final supertile (st = 15, slab 1): 8 instr x 2 rows
  emit4(1, 15, 0);
  emit4(1, 15, 8);

  // ctx epilogue: [b][s][h*64 + d] bf16
  const int b = bh >> 4, h = bh & 15;
  #pragma unroll
  for (int df = 0; df < 4; ++df)
  #pragma unroll
  for (int r = 0; r < 4; ++r){
    const int qq = q0 + hi*4 + r;
    const int d  = df*16 + lo;
    ctx[((size_t)b * S + qq) * DMODEL + h*DK + d] = f2bf(o[df][r]);
  }
}

// ---------- launch ----------
extern "C" void kernel_launch(void* const* d_in, const int* in_sizes, int n_in,
                              void* d_out, int out_size, void* d_ws, size_t ws_size,
                              hipStream_t stream)
{
  const float* q_in = (const float*)d_in[0];
  const float* k_in = (const float*)d_in[1];
  const float* v_in = (const float*)d_in[2];
  const float* wq   = (const float*)d_in[3];
  const float* wk   = (const float*)d_in[4];
  const float* wv   = (const float*)d_in[5];
  const float* wo   = (const float*)d_in[6];
  const float* bo   = (const float*)d_in[7];

  u16* ws = (u16*)d_ws;
  u16* X  = ws;                                          // Xq,Xk,Xv contiguous
  u16* W  = ws + (size_t)3*NROWS*DMODEL;                 // Wq,Wk,Wv,Wo contiguous
  u16* Wob= W  + (size_t)3*DMODEL*DMODEL;
  u16* Qh = W  + (size_t)4*DMODEL*DMODEL;
  u16* Kh = Qh + (size_t)NROWS*DMODEL;
  u16* Vt = Kh + (size_t)NROWS*DMODEL;
  u16* Ctx= Vt + (size_t)NROWS*DMODEL;                   // total 64 MiB

  cvt_all<<<dim3(4096, 7), 256, 0, stream>>>(q_in, k_in, v_in, wq, wk, wv, wo, ws);

  gemm_mha<false><<<dim3(32, 8, 3), 256, 0, stream>>>(X, W, Qh, Kh, Vt, nullptr, nullptr);

  float* out0 = (float*)d_out;
  float* attn = out0 + (size_t)NROWS * DMODEL;
  attn_fused<<<dim3(512), 512, 0, stream>>>(Qh, Kh, Vt, attn, Ctx);

  gemm_mha<true><<<dim3(32, 8), 256, 0, stream>>>(Ctx, Wob, nullptr, nullptr, nullptr, out0, bo);
}

// Round 8
// 227.450 us; speedup vs baseline: 1.3129x; 1.3129x over previous
//
#include <hip/hip_runtime.h>
#include <hip/hip_bf16.h>

typedef unsigned int u32;
typedef unsigned short u16;
using bf16x8 = __attribute__((ext_vector_type(8))) short;
using f32x4  = __attribute__((ext_vector_type(4))) float;

#define S_LEN 2048
#define DK 64
#define NH 16
#define DMODEL 1024
#define NROWS 4096   // B * S

// ---------- helpers ----------
__device__ __forceinline__ u16 f2bf(float f){
  u32 u = __builtin_bit_cast(u32, f);
  u += 0x7fffu + ((u >> 16) & 1u);   // round-to-nearest-even
  return (u16)(u >> 16);
}

__device__ __forceinline__ void gload_lds16(const u16* g, u16* l){
  // async global->LDS, 16B per lane; LDS dest = wave-uniform base + lane*16
  __builtin_amdgcn_global_load_lds(
      (__attribute__((address_space(1))) u32*)(void*)const_cast<u16*>(g),
      (__attribute__((address_space(3))) u32*)(void*)l, 16, 0, 0);
}

// counted-vmcnt barrier: 2 staging loads (oldest) guaranteed done,
// 4 attn stores may remain in flight across the barrier.
#define TILE_BARRIER_VM4() do { \
  asm volatile("s_waitcnt vmcnt(4) lgkmcnt(0)" ::: "memory"); \
  __builtin_amdgcn_s_barrier(); \
  __builtin_amdgcn_sched_barrier(0); \
} while (0)

#define TILE_BARRIER_VM0() do { \
  asm volatile("s_waitcnt vmcnt(0) lgkmcnt(0)" ::: "memory"); \
  __builtin_amdgcn_s_barrier(); \
  __builtin_amdgcn_sched_barrier(0); \
} while (0)

// ---------- f32 -> bf16 conversion, all 7 tensors in one launch ----------
__global__ void cvt_all(const float* __restrict__ q, const float* __restrict__ k,
                        const float* __restrict__ v, const float* __restrict__ wq,
                        const float* __restrict__ wk, const float* __restrict__ wv,
                        const float* __restrict__ wo, u16* __restrict__ ws)
{
  const int y = blockIdx.y;
  const int n4 = (y < 3) ? (NROWS*DMODEL/4) : (DMODEL*DMODEL/4);
  const int i = blockIdx.x * blockDim.x + threadIdx.x;
  if (i >= n4) return;
  const float* src = (y==0)?q:(y==1)?k:(y==2)?v:(y==3)?wq:(y==4)?wk:(y==5)?wv:wo;
  u16* dst = ws + ((y < 3) ? (size_t)y*(NROWS*DMODEL)
                           : (size_t)3*(NROWS*DMODEL) + (size_t)(y-3)*(DMODEL*DMODEL));
  float4 val = reinterpret_cast<const float4*>(src)[i];
  ushort4 o;
  o.x = f2bf(val.x); o.y = f2bf(val.y); o.z = f2bf(val.z); o.w = f2bf(val.w);
  reinterpret_cast<ushort4*>(dst)[i] = o;
}

// ---------- GEMM core (m97 structure): C[m,n] = sum_k A[m,k]*Bt[n,k], K=1024 ----------
template<bool OUTGEMM>
__global__ __launch_bounds__(256)
void gemm_mha(const u16* __restrict__ Abase, const u16* __restrict__ Bbase,
              u16* __restrict__ Qh, u16* __restrict__ Kh, u16* __restrict__ Vt,
              float* __restrict__ Out, const float* __restrict__ bias)
{
  __shared__ u16 smem[32768];          // 64 KiB: As [2][8192] | Bs [2][8192]
  u16* As = smem;
  u16* Bs = smem + 16384;

  const int tid  = threadIdx.x;
  const int lane = tid & 63;
  const int wid  = tid >> 6;            // 4 waves
  const int lo = lane & 15, hi = lane >> 4;
  const int z = OUTGEMM ? 0 : blockIdx.z;
  const int m0 = blockIdx.x * 128;
  const int n0 = blockIdx.y * 128;
  const u16* ga = Abase + (size_t)z * (NROWS*DMODEL)  + (size_t)m0 * DMODEL;
  const u16* gb = Bbase + (size_t)z * (DMODEL*DMODEL) + (size_t)n0 * DMODEL;

  const int wm = (wid >> 1) * 64;
  const int wn = (wid & 1) * 64;

  f32x4 acc[4][4] = {};

  auto stage = [&](int buf, int kt){
    const u16* a = ga + kt * 64;
    const u16* b = gb + kt * 64;
    #pragma unroll
    for (int i = 0; i < 4; ++i){
      const int chunk = i*256 + tid;    // 1024 16B-chunks (128 rows x 8)
      const int row = chunk >> 3, c8 = chunk & 7;
      gload_lds16(a + (size_t)row*DMODEL + c8*8, &As[buf*8192 + (i*256 + wid*64)*8]);
      gload_lds16(b + (size_t)row*DMODEL + c8*8, &Bs[buf*8192 + (i*256 + wid*64)*8]);
    }
  };

  stage(0, 0);
  __syncthreads();

  for (int t = 0; t < DMODEL/64; ++t){
    const int buf = t & 1;
    if (t + 1 < DMODEL/64) stage(buf ^ 1, t + 1);
    const u16* as = &As[buf*8192];
    const u16* bs = &Bs[buf*8192];
    #pragma unroll
    for (int ks = 0; ks < 2; ++ks){
      bf16x8 af[4], bfr[4];
      #pragma unroll
      for (int i = 0; i < 4; ++i){
        af[i]  = *reinterpret_cast<const bf16x8*>(&as[(wm + i*16 + lo)*64 + ks*32 + hi*8]);
        bfr[i] = *reinterpret_cast<const bf16x8*>(&bs[(wn + i*16 + lo)*64 + ks*32 + hi*8]);
      }
      #pragma unroll
      for (int mi = 0; mi < 4; ++mi)
        #pragma unroll
        for (int ni = 0; ni < 4; ++ni)
          acc[mi][ni] = __builtin_amdgcn_mfma_f32_16x16x32_bf16(af[mi], bfr[ni], acc[mi][ni], 0, 0, 0);
    }
    __syncthreads();
  }

  // C/D layout: col = lane&15 (lo), row = hi*4 + r
  if constexpr (OUTGEMM){
    #pragma unroll
    for (int mi = 0; mi < 4; ++mi)
    #pragma unroll
    for (int ni = 0; ni < 4; ++ni)
    #pragma unroll
    for (int r = 0; r < 4; ++r){
      const int m = m0 + wm + mi*16 + hi*4 + r;
      const int n = n0 + wn + ni*16 + lo;
      Out[(size_t)m * DMODEL + n] = acc[mi][ni][r] + bias[n];
    }
  } else {
    // LDS transpose epilogue; row pitch 136 keeps 16B alignment, banks spread
    const float scale = (z == 0) ? 0.18033688011112043f : 1.0f;  // log2(e)/8
    if (z == 2){
      #pragma unroll
      for (int mi = 0; mi < 4; ++mi)
      #pragma unroll
      for (int ni = 0; ni < 4; ++ni)
      #pragma unroll
      for (int r = 0; r < 4; ++r)
        smem[(size_t)(wn + ni*16 + lo)*136 + wm + mi*16 + hi*4 + r] = f2bf(acc[mi][ni][r]);
    } else {
      #pragma unroll
      for (int mi = 0; mi < 4; ++mi)
      #pragma unroll
      for (int ni = 0; ni < 4; ++ni)
      #pragma unroll
      for (int r = 0; r < 4; ++r)
        smem[(size_t)(wm + mi*16 + hi*4 + r)*136 + wn + ni*16 + lo] = f2bf(acc[mi][ni][r] * scale);
    }
    __syncthreads();
    const int b = m0 >> 11, s0 = m0 & 2047;
    #pragma unroll
    for (int it = 0; it < 8; ++it){
      const int c = it*256 + tid;       // 2048 chunks of 8 elements
      const int rr = c >> 4, cc = c & 15;
      bf16x8 v = *reinterpret_cast<const bf16x8*>(&smem[(size_t)rr*136 + cc*8]);
      if (z == 2){
        const int gn = n0 + rr, h = gn >> 6, d = gn & 63;
        *reinterpret_cast<bf16x8*>(&Vt[(((size_t)(b*NH + h))*DK + d)*S_LEN + s0 + cc*8]) = v;
      } else {
        const int gn = n0 + cc*8, h = gn >> 6, d0 = gn & 63;
        u16* dst = z ? Kh : Qh;
        *reinterpret_cast<bf16x8*>(&dst[(((size_t)(b*NH + h))*S_LEN + s0 + rr)*DK + d0]) = v;
      }
    }
  }
}

// ---------- fused attention: 8 waves x 16 q-rows, nontemporal attn stores ----------
// 512 blocks (XCD-swizzled), 512 threads. K/V double-buffered in LDS
// (global_load_lds, XOR-chunk swizzle). Coalesced attn stores via per-wave
// f32 P-tile (pitch 40), emitted NONTEMPORAL (bypass L2 allocation — the
// 537MB attn output is write-once-never-read; dirty-line alloc/evict in the
// 4MB/XCD L2 is the suspected 2.7 TB/s cap). Counted-vmcnt barriers keep
// stores in flight.
__global__ __launch_bounds__(512)
void attn_fused(const u16* __restrict__ Qh, const u16* __restrict__ Kh,
                const u16* __restrict__ Vt, float* __restrict__ attn,
                u16* __restrict__ ctx)
{
  constexpr int S = S_LEN;
  __shared__ u16 Ks[2][64*64];       // 16 KiB, swizzled
  __shared__ u16 Vs[2][64*64];       // 16 KiB, swizzled
  __shared__ float Pf[8][16*40];     // 20 KiB, per-wave P half-tile (16q x 32k)

  const int tid = threadIdx.x, lane = tid & 63, w = tid >> 6;   // 8 waves
  const int lo = lane & 15, hi = lane >> 4;

  // bijective XCD mapping: 16 q-tiles of one (b,h) share an XCD
  const int idx = blockIdx.x;
  const int slot = idx >> 3;
  const int qt = slot & 15;
  const int bh = (idx & 7) + 8 * (slot >> 4);

  const int q0 = qt*128 + w*16;      // this wave's 16 q rows
  const u16* Qb = Qh + (size_t)bh * S * DK;
  const u16* Kb = Kh + (size_t)bh * S * DK;
  const u16* Vb = Vt + (size_t)bh * DK * S;
  float* attn_b = attn + (size_t)bh * S * S;

  // Q fragments in registers for the whole kernel
  bf16x8 aq[2];
  #pragma unroll
  for (int ks = 0; ks < 2; ++ks)
    aq[ks] = *reinterpret_cast<const bf16x8*>(
        &Qb[(size_t)(q0 + lo) * DK + ks*32 + hi*8]);

  // swizzled staging: LDS[r][c] (16B chunks) <- G[r][c ^ (r&7)]; 1 chunk/lane
  const int sr = tid >> 3, sc = tid & 7;
  auto stageK = [&](int buf, int t){
    gload_lds16(Kb + (size_t)t*64*DK + (size_t)sr*DK + ((sc ^ (sr&7))*8),
                &Ks[buf][w*512]);
  };
  auto stageV = [&](int buf, int t){
    gload_lds16(Vb + (size_t)sr*S + t*64 + ((sc ^ (sr&7))*8),
                &Vs[buf][w*512]);
  };

  auto qk = [&](int buf, f32x4 (&s)[4]){
    #pragma unroll
    for (int ks = 0; ks < 2; ++ks){
      bf16x8 bk[4];
      #pragma unroll
      for (int kf = 0; kf < 4; ++kf){
        const int row = kf*16 + lo;
        bk[kf] = *reinterpret_cast<const bf16x8*>(
            &Ks[buf][row*64 + (((ks*4 + hi) ^ (row&7))*8)]);
      }
      #pragma unroll
      for (int kf = 0; kf < 4; ++kf)
        s[kf] = __builtin_amdgcn_mfma_f32_16x16x32_bf16(aq[ks], bk[kf], s[kf], 0, 0, 0);
    }
  };

  // ---- pass 1: lane-local sum of exp2(s') ----
  stageK(0, 0);
  __syncthreads();
  float l_part[4] = {};
  for (int t = 0; t < S/64; ++t){
    const int buf = t & 1;
    if (t + 1 < S/64) stageK(buf ^ 1, t + 1);
    f32x4 s[4] = {};
    qk(buf, s);
    #pragma unroll
    for (int r = 0; r < 4; ++r)
      l_part[r] += exp2f(s[0][r]) + exp2f(s[1][r]) + exp2f(s[2][r]) + exp2f(s[3][r]);
    __syncthreads();
  }

  float inv_l[4];
  #pragma unroll
  for (int r = 0; r < 4; ++r){
    float v = l_part[r];
    v += __shfl_xor(v, 1, 64);
    v += __shfl_xor(v, 2, 64);
    v += __shfl_xor(v, 4, 64);
    v += __shfl_xor(v, 8, 64);
    inv_l[r] = 1.0f / v;
  }

  // ---- pass 2: normalized p -> nontemporal coalesced attn stores + PV ----
  // per lane per tile: 2 gload_lds (K,V for t+1), then 4 dwordx4 nt-stores.
  stageK(0, 0); stageV(0, 0);
  TILE_BARRIER_VM0();
  f32x4 o[4] = {};
  for (int t = 0; t < S/64; ++t){
    const int buf = t & 1;
    if (t + 1 < S/64){ stageK(buf ^ 1, t + 1); stageV(buf ^ 1, t + 1); }
    f32x4 s[4] = {};
    qk(buf, s);

    #pragma unroll
    for (int half = 0; half < 2; ++half){
      // normalized p (f32) into per-wave tile, chunk-XOR swizzled, pitch 40
      #pragma unroll
      for (int k2 = 0; k2 < 2; ++k2){
        const int kf = half*2 + k2;
        #pragma unroll
        for (int r = 0; r < 4; ++r){
          const int row = hi*4 + r;
          const int col = k2*16 + lo;
          Pf[w][row*40 + ((((col>>2) ^ (row&7)) << 2) | (col & 3))] =
              exp2f(s[kf][r]) * inv_l[r];
        }
      }
      // coalesced NONTEMPORAL attn store: full 128B lines, L2-bypassing
      #pragma unroll
      for (int j = 0; j < 2; ++j){
        const int row = j*8 + (lane >> 3);
        const int cb  = (lane & 7) * 4;
        f32x4 vv = *reinterpret_cast<const f32x4*>(
            &Pf[w][row*40 + ((((cb>>2) ^ (row&7)) << 2))]);
        __builtin_nontemporal_store(vv, reinterpret_cast<f32x4*>(
            &attn_b[(size_t)(q0 + row)*S + t*64 + half*32 + cb]));
      }
      // PV A-fragment from Pf
      {
        const int row = lo;
        const f32x4 pa = *reinterpret_cast<const f32x4*>(
            &Pf[w][row*40 + (((2*hi) ^ (row&7)) << 2)]);
        const f32x4 pb = *reinterpret_cast<const f32x4*>(
            &Pf[w][row*40 + (((2*hi + 1) ^ (row&7)) << 2)]);
        union { bf16x8 v; __hip_bfloat162 h[4]; } u_;
        u_.h[0] = __float22bfloat162_rn(float2{pa[0], pa[1]});
        u_.h[1] = __float22bfloat162_rn(float2{pa[2], pa[3]});
        u_.h[2] = __float22bfloat162_rn(float2{pb[0], pb[1]});
        u_.h[3] = __float22bfloat162_rn(float2{pb[2], pb[3]});
        bf16x8 bv[4];
        #pragma unroll
        for (int df = 0; df < 4; ++df){
          const int vrow = df*16 + lo;
          bv[df] = *reinterpret_cast<const bf16x8*>(
              &Vs[buf][vrow*64 + (((half*4 + hi) ^ (vrow&7))*8)]);
        }
        #pragma unroll
        for (int df = 0; df < 4; ++df)
          o[df] = __builtin_amdgcn_mfma_f32_16x16x32_bf16(u_.v, bv[df], o[df], 0, 0, 0);
      }
    }

    if (t + 1 < S/64){
      // 2 staging loads (oldest) done; 4 attn stores may stay in flight
      TILE_BARRIER_VM4();
    }
  }

  // ctx epilogue: [b][s][h*64 + d] bf16
  const int b = bh >> 4, h = bh & 15;
  #pragma unroll
  for (int df = 0; df < 4; ++df)
  #pragma unroll
  for (int r = 0; r < 4; ++r){
    const int qq = q0 + hi*4 + r;
    const int d  = df*16 + lo;
    ctx[((size_t)b * S + qq) * DMODEL + h*DK + d] = f2bf(o[df][r]);
  }
}

// ---------- launch ----------
extern "C" void kernel_launch(void* const* d_in, const int* in_sizes, int n_in,
                              void* d_out, int out_size, void* d_ws, size_t ws_size,
                              hipStream_t stream)
{
  const float* q_in = (const float*)d_in[0];
  const float* k_in = (const float*)d_in[1];
  const float* v_in = (const float*)d_in[2];
  const float* wq   = (const float*)d_in[3];
  const float* wk   = (const float*)d_in[4];
  const float* wv   = (const float*)d_in[5];
  const float* wo   = (const float*)d_in[6];
  const float* bo   = (const float*)d_in[7];

  u16* ws = (u16*)d_ws;
  u16* X  = ws;                                          // Xq,Xk,Xv contiguous
  u16* W  = ws + (size_t)3*NROWS*DMODEL;                 // Wq,Wk,Wv,Wo contiguous
  u16* Wob= W  + (size_t)3*DMODEL*DMODEL;
  u16* Qh = W  + (size_t)4*DMODEL*DMODEL;
  u16* Kh = Qh + (size_t)NROWS*DMODEL;
  u16* Vt = Kh + (size_t)NROWS*DMODEL;
  u16* Ctx= Vt + (size_t)NROWS*DMODEL;                   // total 64 MiB

  cvt_all<<<dim3(4096, 7), 256, 0, stream>>>(q_in, k_in, v_in, wq, wk, wv, wo, ws);

  gemm_mha<false><<<dim3(32, 8, 3), 256, 0, stream>>>(X, W, Qh, Kh, Vt, nullptr, nullptr);

  float* out0 = (float*)d_out;
  float* attn = out0 + (size_t)NROWS * DMODEL;
  attn_fused<<<dim3(512), 512, 0, stream>>>(Qh, Kh, Vt, attn, Ctx);

  gemm_mha<true><<<dim3(32, 8), 256, 0, stream>>>(Ctx, Wob, nullptr, nullptr, nullptr, out0, bo);
}

// Round 9
// 220.889 us; speedup vs baseline: 1.3519x; 1.0297x over previous
//
#include <hip/hip_runtime.h>
#include <hip/hip_bf16.h>

typedef unsigned int u32;
typedef unsigned short u16;
using bf16x8 = __attribute__((ext_vector_type(8))) short;
using f32x4  = __attribute__((ext_vector_type(4))) float;

#define S_LEN 2048
#define DK 64
#define NH 16
#define DMODEL 1024
#define NROWS 4096   // B * S

// ---------- helpers ----------
__device__ __forceinline__ u16 f2bf(float f){
  u32 u = __builtin_bit_cast(u32, f);
  u += 0x7fffu + ((u >> 16) & 1u);   // round-to-nearest-even
  return (u16)(u >> 16);
}

__device__ __forceinline__ void gload_lds16(const u16* g, u16* l){
  // async global->LDS, 16B per lane; LDS dest = wave-uniform base + lane*16
  __builtin_amdgcn_global_load_lds(
      (__attribute__((address_space(1))) u32*)(void*)const_cast<u16*>(g),
      (__attribute__((address_space(3))) u32*)(void*)l, 16, 0, 0);
}

// counted-vmcnt barrier: 2 staging loads (oldest) guaranteed done,
// 4 attn stores may remain in flight across the barrier.
#define TILE_BARRIER_VM4() do { \
  asm volatile("s_waitcnt vmcnt(4) lgkmcnt(0)" ::: "memory"); \
  __builtin_amdgcn_s_barrier(); \
  __builtin_amdgcn_sched_barrier(0); \
} while (0)

#define TILE_BARRIER_VM0() do { \
  asm volatile("s_waitcnt vmcnt(0) lgkmcnt(0)" ::: "memory"); \
  __builtin_amdgcn_s_barrier(); \
  __builtin_amdgcn_sched_barrier(0); \
} while (0)

// ---------- f32 -> bf16 conversion, all 7 tensors in one launch ----------
__global__ void cvt_all(const float* __restrict__ q, const float* __restrict__ k,
                        const float* __restrict__ v, const float* __restrict__ wq,
                        const float* __restrict__ wk, const float* __restrict__ wv,
                        const float* __restrict__ wo, u16* __restrict__ ws)
{
  const int y = blockIdx.y;
  const int n4 = (y < 3) ? (NROWS*DMODEL/4) : (DMODEL*DMODEL/4);
  const int i = blockIdx.x * blockDim.x + threadIdx.x;
  if (i >= n4) return;
  const float* src = (y==0)?q:(y==1)?k:(y==2)?v:(y==3)?wq:(y==4)?wk:(y==5)?wv:wo;
  u16* dst = ws + ((y < 3) ? (size_t)y*(NROWS*DMODEL)
                           : (size_t)3*(NROWS*DMODEL) + (size_t)(y-3)*(DMODEL*DMODEL));
  float4 val = reinterpret_cast<const float4*>(src)[i];
  ushort4 o;
  o.x = f2bf(val.x); o.y = f2bf(val.y); o.z = f2bf(val.z); o.w = f2bf(val.w);
  reinterpret_cast<ushort4*>(dst)[i] = o;
}

// ---------- GEMM core (m97 structure): C[m,n] = sum_k A[m,k]*Bt[n,k], K=1024 ----------
template<bool OUTGEMM>
__global__ __launch_bounds__(256)
void gemm_mha(const u16* __restrict__ Abase, const u16* __restrict__ Bbase,
              u16* __restrict__ Qh, u16* __restrict__ Kh, u16* __restrict__ Vt,
              float* __restrict__ Out, const float* __restrict__ bias)
{
  __shared__ u16 smem[32768];          // 64 KiB: As [2][8192] | Bs [2][8192]
  u16* As = smem;
  u16* Bs = smem + 16384;

  const int tid  = threadIdx.x;
  const int lane = tid & 63;
  const int wid  = tid >> 6;            // 4 waves
  const int lo = lane & 15, hi = lane >> 4;
  const int z = OUTGEMM ? 0 : blockIdx.z;
  const int m0 = blockIdx.x * 128;
  const int n0 = blockIdx.y * 128;
  const u16* ga = Abase + (size_t)z * (NROWS*DMODEL)  + (size_t)m0 * DMODEL;
  const u16* gb = Bbase + (size_t)z * (DMODEL*DMODEL) + (size_t)n0 * DMODEL;

  const int wm = (wid >> 1) * 64;
  const int wn = (wid & 1) * 64;

  f32x4 acc[4][4] = {};

  auto stage = [&](int buf, int kt){
    const u16* a = ga + kt * 64;
    const u16* b = gb + kt * 64;
    #pragma unroll
    for (int i = 0; i < 4; ++i){
      const int chunk = i*256 + tid;    // 1024 16B-chunks (128 rows x 8)
      const int row = chunk >> 3, c8 = chunk & 7;
      gload_lds16(a + (size_t)row*DMODEL + c8*8, &As[buf*8192 + (i*256 + wid*64)*8]);
      gload_lds16(b + (size_t)row*DMODEL + c8*8, &Bs[buf*8192 + (i*256 + wid*64)*8]);
    }
  };

  stage(0, 0);
  __syncthreads();

  for (int t = 0; t < DMODEL/64; ++t){
    const int buf = t & 1;
    if (t + 1 < DMODEL/64) stage(buf ^ 1, t + 1);
    const u16* as = &As[buf*8192];
    const u16* bs = &Bs[buf*8192];
    #pragma unroll
    for (int ks = 0; ks < 2; ++ks){
      bf16x8 af[4], bfr[4];
      #pragma unroll
      for (int i = 0; i < 4; ++i){
        af[i]  = *reinterpret_cast<const bf16x8*>(&as[(wm + i*16 + lo)*64 + ks*32 + hi*8]);
        bfr[i] = *reinterpret_cast<const bf16x8*>(&bs[(wn + i*16 + lo)*64 + ks*32 + hi*8]);
      }
      #pragma unroll
      for (int mi = 0; mi < 4; ++mi)
        #pragma unroll
        for (int ni = 0; ni < 4; ++ni)
          acc[mi][ni] = __builtin_amdgcn_mfma_f32_16x16x32_bf16(af[mi], bfr[ni], acc[mi][ni], 0, 0, 0);
    }
    __syncthreads();
  }

  // C/D layout: col = lane&15 (lo), row = hi*4 + r
  if constexpr (OUTGEMM){
    #pragma unroll
    for (int mi = 0; mi < 4; ++mi)
    #pragma unroll
    for (int ni = 0; ni < 4; ++ni)
    #pragma unroll
    for (int r = 0; r < 4; ++r){
      const int m = m0 + wm + mi*16 + hi*4 + r;
      const int n = n0 + wn + ni*16 + lo;
      // out0 is write-once-never-read: bypass L2 allocation
      __builtin_nontemporal_store(acc[mi][ni][r] + bias[n],
                                  &Out[(size_t)m * DMODEL + n]);
    }
  } else {
    // LDS transpose epilogue; row pitch 136 keeps 16B alignment, banks spread
    const float scale = (z == 0) ? 0.18033688011112043f : 1.0f;  // log2(e)/8
    if (z == 2){
      #pragma unroll
      for (int mi = 0; mi < 4; ++mi)
      #pragma unroll
      for (int ni = 0; ni < 4; ++ni)
      #pragma unroll
      for (int r = 0; r < 4; ++r)
        smem[(size_t)(wn + ni*16 + lo)*136 + wm + mi*16 + hi*4 + r] = f2bf(acc[mi][ni][r]);
    } else {
      #pragma unroll
      for (int mi = 0; mi < 4; ++mi)
      #pragma unroll
      for (int ni = 0; ni < 4; ++ni)
      #pragma unroll
      for (int r = 0; r < 4; ++r)
        smem[(size_t)(wm + mi*16 + hi*4 + r)*136 + wn + ni*16 + lo] = f2bf(acc[mi][ni][r] * scale);
    }
    __syncthreads();
    const int b = m0 >> 11, s0 = m0 & 2047;
    #pragma unroll
    for (int it = 0; it < 8; ++it){
      const int c = it*256 + tid;       // 2048 chunks of 8 elements
      const int rr = c >> 4, cc = c & 15;
      bf16x8 v = *reinterpret_cast<const bf16x8*>(&smem[(size_t)rr*136 + cc*8]);
      if (z == 2){
        const int gn = n0 + rr, h = gn >> 6, d = gn & 63;
        *reinterpret_cast<bf16x8*>(&Vt[(((size_t)(b*NH + h))*DK + d)*S_LEN + s0 + cc*8]) = v;
      } else {
        const int gn = n0 + cc*8, h = gn >> 6, d0 = gn & 63;
        u16* dst = z ? Kh : Qh;
        *reinterpret_cast<bf16x8*>(&dst[(((size_t)(b*NH + h))*S_LEN + s0 + rr)*DK + d0]) = v;
      }
    }
  }
}

// ---------- fused attention ----------
// 512 blocks (XCD-swizzled), 512 threads = 8 waves x 16 q-rows.
// Pass 1: 128-row K-tiles double-buffered in the SAME LDS that pass 2 uses
// for K+V (aliased) -> 16 barriers instead of 32.
// Pass 2: 64-row K+V tiles, nontemporal coalesced attn stores via per-wave
// f32 P-tile, counted-vmcnt barriers keep stores in flight.
__global__ __launch_bounds__(512)
void attn_fused(const u16* __restrict__ Qh, const u16* __restrict__ Kh,
                const u16* __restrict__ Vt, float* __restrict__ attn,
                u16* __restrict__ ctx)
{
  constexpr int S = S_LEN;
  __shared__ u16 KV[2][2][64*64];    // 32 KiB: pass2 [buf][K|V]; pass1 [buf] = 128-row K
  __shared__ float Pf[8][16*40];     // 20 KiB, per-wave P half-tile (16q x 32k)

  const int tid = threadIdx.x, lane = tid & 63, w = tid >> 6;   // 8 waves
  const int lo = lane & 15, hi = lane >> 4;

  // bijective XCD mapping: 16 q-tiles of one (b,h) share an XCD
  const int idx = blockIdx.x;
  const int slot = idx >> 3;
  const int qt = slot & 15;
  const int bh = (idx & 7) + 8 * (slot >> 4);

  const int q0 = qt*128 + w*16;      // this wave's 16 q rows
  const u16* Qb = Qh + (size_t)bh * S * DK;
  const u16* Kb = Kh + (size_t)bh * S * DK;
  const u16* Vb = Vt + (size_t)bh * DK * S;
  float* attn_b = attn + (size_t)bh * S * S;

  // Q fragments in registers for the whole kernel
  bf16x8 aq[2];
  #pragma unroll
  for (int ks = 0; ks < 2; ++ks)
    aq[ks] = *reinterpret_cast<const bf16x8*>(
        &Qb[(size_t)(q0 + lo) * DK + ks*32 + hi*8]);

  // qk on a 64x64 swizzled tile at `tile`
  auto qk = [&](const u16* tile, f32x4 (&s)[4]){
    #pragma unroll
    for (int ks = 0; ks < 2; ++ks){
      bf16x8 bk[4];
      #pragma unroll
      for (int kf = 0; kf < 4; ++kf){
        const int row = kf*16 + lo;
        bk[kf] = *reinterpret_cast<const bf16x8*>(
            &tile[row*64 + (((ks*4 + hi) ^ (row&7))*8)]);
      }
      #pragma unroll
      for (int kf = 0; kf < 4; ++kf)
        s[kf] = __builtin_amdgcn_mfma_f32_16x16x32_bf16(aq[ks], bk[kf], s[kf], 0, 0, 0);
    }
  };

  // ---- pass 1: 128-row K tiles (LDS aliased over pass2's K+V), 16 barriers ----
  {
    u16* KP0 = &KV[0][0][0];         // 128x64 = 8192 u16 per buf (K|V contiguous)
    u16* KP1 = &KV[1][0][0];
    // stage 128 rows: 1024 chunks, 2 per lane
    auto stage128 = [&](u16* dst, int t16){
      const u16* kt = Kb + (size_t)t16 * 128 * DK;
      #pragma unroll
      for (int i = 0; i < 2; ++i){
        const int u_ = i*512 + tid;
        const int r = u_ >> 3, c = u_ & 7;
        gload_lds16(kt + (size_t)r*DK + ((c ^ (r&7))*8), dst + (i*512 + w*64)*8);
      }
    };
    stage128(KP0, 0);
    __syncthreads();
    float l_part[4] = {};
    for (int t = 0; t < S/128; ++t){
      u16* cur = (t & 1) ? KP1 : KP0;
      u16* nxt = (t & 1) ? KP0 : KP1;
      if (t + 1 < S/128) stage128(nxt, t + 1);
      #pragma unroll
      for (int sub = 0; sub < 2; ++sub){
        f32x4 s[4] = {};
        qk(cur + sub*4096, s);
        #pragma unroll
        for (int r = 0; r < 4; ++r)
          l_part[r] += exp2f(s[0][r]) + exp2f(s[1][r]) + exp2f(s[2][r]) + exp2f(s[3][r]);
      }
      __syncthreads();
    }
    float inv_l[4];
    #pragma unroll
    for (int r = 0; r < 4; ++r){
      float v = l_part[r];
      v += __shfl_xor(v, 1, 64);
      v += __shfl_xor(v, 2, 64);
      v += __shfl_xor(v, 4, 64);
      v += __shfl_xor(v, 8, 64);
      inv_l[r] = 1.0f / v;
    }

    // ---- pass 2: K+V 64-row tiles, nt stores ----
    const int sr = tid >> 3, sc = tid & 7;
    auto stageK = [&](int buf, int t){
      gload_lds16(Kb + (size_t)t*64*DK + (size_t)sr*DK + ((sc ^ (sr&7))*8),
                  &KV[buf][0][w*512]);
    };
    auto stageV = [&](int buf, int t){
      gload_lds16(Vb + (size_t)sr*S + t*64 + ((sc ^ (sr&7))*8),
                  &KV[buf][1][w*512]);
    };

    stageK(0, 0); stageV(0, 0);
    TILE_BARRIER_VM0();
    f32x4 o[4] = {};
    for (int t = 0; t < S/64; ++t){
      const int buf = t & 1;
      if (t + 1 < S/64){ stageK(buf ^ 1, t + 1); stageV(buf ^ 1, t + 1); }
      f32x4 s[4] = {};
      qk(&KV[buf][0][0], s);

      #pragma unroll
      for (int half = 0; half < 2; ++half){
        // normalized p (f32) into per-wave tile, chunk-XOR swizzled, pitch 40
        #pragma unroll
        for (int k2 = 0; k2 < 2; ++k2){
          const int kf = half*2 + k2;
          #pragma unroll
          for (int r = 0; r < 4; ++r){
            const int row = hi*4 + r;
            const int col = k2*16 + lo;
            Pf[w][row*40 + ((((col>>2) ^ (row&7)) << 2) | (col & 3))] =
                exp2f(s[kf][r]) * inv_l[r];
          }
        }
        // coalesced NONTEMPORAL attn store: full 128B lines, L2-bypassing
        #pragma unroll
        for (int j = 0; j < 2; ++j){
          const int row = j*8 + (lane >> 3);
          const int cb  = (lane & 7) * 4;
          f32x4 vv = *reinterpret_cast<const f32x4*>(
              &Pf[w][row*40 + ((((cb>>2) ^ (row&7)) << 2))]);
          __builtin_nontemporal_store(vv, reinterpret_cast<f32x4*>(
              &attn_b[(size_t)(q0 + row)*S + t*64 + half*32 + cb]));
        }
        // PV A-fragment from Pf
        {
          const int row = lo;
          const f32x4 pa = *reinterpret_cast<const f32x4*>(
              &Pf[w][row*40 + (((2*hi) ^ (row&7)) << 2)]);
          const f32x4 pb = *reinterpret_cast<const f32x4*>(
              &Pf[w][row*40 + (((2*hi + 1) ^ (row&7)) << 2)]);
          union { bf16x8 v; __hip_bfloat162 h[4]; } u_;
          u_.h[0] = __float22bfloat162_rn(float2{pa[0], pa[1]});
          u_.h[1] = __float22bfloat162_rn(float2{pa[2], pa[3]});
          u_.h[2] = __float22bfloat162_rn(float2{pb[0], pb[1]});
          u_.h[3] = __float22bfloat162_rn(float2{pb[2], pb[3]});
          bf16x8 bv[4];
          #pragma unroll
          for (int df = 0; df < 4; ++df){
            const int vrow = df*16 + lo;
            bv[df] = *reinterpret_cast<const bf16x8*>(
                &KV[buf][1][vrow*64 + (((half*4 + hi) ^ (vrow&7))*8)]);
          }
          #pragma unroll
          for (int df = 0; df < 4; ++df)
            o[df] = __builtin_amdgcn_mfma_f32_16x16x32_bf16(u_.v, bv[df], o[df], 0, 0, 0);
        }
      }

      if (t + 1 < S/64){
        // 2 staging loads (oldest) done; 4 attn stores may stay in flight
        TILE_BARRIER_VM4();
      }
    }

    // ctx epilogue: [b][s][h*64 + d] bf16
    const int b = bh >> 4, h = bh & 15;
    #pragma unroll
    for (int df = 0; df < 4; ++df)
    #pragma unroll
    for (int r = 0; r < 4; ++r){
      const int qq = q0 + hi*4 + r;
      const int d  = df*16 + lo;
      ctx[((size_t)b * S + qq) * DMODEL + h*DK + d] = f2bf(o[df][r]);
    }
  }
}

// ---------- launch ----------
extern "C" void kernel_launch(void* const* d_in, const int* in_sizes, int n_in,
                              void* d_out, int out_size, void* d_ws, size_t ws_size,
                              hipStream_t stream)
{
  const float* q_in = (const float*)d_in[0];
  const float* k_in = (const float*)d_in[1];
  const float* v_in = (const float*)d_in[2];
  const float* wq   = (const float*)d_in[3];
  const float* wk   = (const float*)d_in[4];
  const float* wv   = (const float*)d_in[5];
  const float* wo   = (const float*)d_in[6];
  const float* bo   = (const float*)d_in[7];

  u16* ws = (u16*)d_ws;
  u16* X  = ws;                                          // Xq,Xk,Xv contiguous
  u16* W  = ws + (size_t)3*NROWS*DMODEL;                 // Wq,Wk,Wv,Wo contiguous
  u16* Wob= W  + (size_t)3*DMODEL*DMODEL;
  u16* Qh = W  + (size_t)4*DMODEL*DMODEL;
  u16* Kh = Qh + (size_t)NROWS*DMODEL;
  u16* Vt = Kh + (size_t)NROWS*DMODEL;
  u16* Ctx= Vt + (size_t)NROWS*DMODEL;                   // total 64 MiB

  cvt_all<<<dim3(4096, 7), 256, 0, stream>>>(q_in, k_in, v_in, wq, wk, wv, wo, ws);

  gemm_mha<false><<<dim3(32, 8, 3), 256, 0, stream>>>(X, W, Qh, Kh, Vt, nullptr, nullptr);

  float* out0 = (float*)d_out;
  float* attn = out0 + (size_t)NROWS * DMODEL;
  attn_fused<<<dim3(512), 512, 0, stream>>>(Qh, Kh, Vt, attn, Ctx);

  gemm_mha<true><<<dim3(32, 8), 256, 0, stream>>>(Ctx, Wob, nullptr, nullptr, nullptr, out0, bo);
}